// Round 1
// 385.459 us; speedup vs baseline: 1.2654x; 1.2654x over previous
//
#include <hip/hip_runtime.h>
#include <stdint.h>

#define C 128

typedef __attribute__((ext_vector_type(8))) short bf16x8;
typedef __attribute__((ext_vector_type(4))) float f32x4;

// f32 -> bf16 bits, round-to-nearest-even
__device__ __forceinline__ uint32_t f2bf1(float f) {
    uint32_t u = __float_as_uint(f);
    return (u + 0x7FFFu + ((u >> 16) & 1u)) >> 16;
}

// ---------------- key packing ----------------
// level-1 key: b1(1)<<23 | z1(5)<<18 | y1(9)<<9 | x1(9); numeric order == lexicographic
// level-2 key: z2(4)<<16 | y2(8)<<8 | x2(8)               (b2 == 0 for all real rows)

__global__ void mark_bits_kernel(const int* __restrict__ coords,
                                 uint32_t* __restrict__ bm1,
                                 uint32_t* __restrict__ bm2, int M) {
    int i = blockIdx.x * blockDim.x + threadIdx.x;
    if (i >= M) return;
    int b = coords[4*i+0], z = coords[4*i+1], y = coords[4*i+2], x = coords[4*i+3];
    uint32_t k1 = ((uint32_t)(b>>1)<<23) | ((uint32_t)(z>>1)<<18) |
                  ((uint32_t)(y>>1)<<9)  | (uint32_t)(x>>1);
    uint32_t k2 = ((uint32_t)(z>>2)<<16) | ((uint32_t)(y>>2)<<8) | (uint32_t)(x>>2);
    atomicOr(&bm1[k1>>5], 1u << (k1 & 31));
    atomicOr(&bm2[k2>>5], 1u << (k2 & 31));
}

// --------------- popcount prefix scan over bitmap words (n multiple of 1024) ---------
__global__ void scan_phase1_kernel(const uint32_t* __restrict__ bm,
                                   uint32_t* __restrict__ bs) {
    __shared__ uint32_t s[256];
    int t = threadIdx.x;
    int base = blockIdx.x * 1024 + t * 4;
    uint32_t sum = __popc(bm[base]) + __popc(bm[base+1]) +
                   __popc(bm[base+2]) + __popc(bm[base+3]);
    s[t] = sum;
    __syncthreads();
    for (int off = 128; off > 0; off >>= 1) {
        if (t < off) s[t] += s[t + off];
        __syncthreads();
    }
    if (t == 0) bs[blockIdx.x] = s[0];
}

// single block exclusive scan of block sums (nb <= 512), writes total
__global__ void scan_phase2_kernel(uint32_t* __restrict__ bs,
                                   uint32_t* __restrict__ total, int nb) {
    __shared__ uint32_t s[512];
    int t = threadIdx.x;
    uint32_t v = (t < nb) ? bs[t] : 0u;
    s[t] = v;
    __syncthreads();
    for (int off = 1; off < 512; off <<= 1) {
        uint32_t add = (t >= off) ? s[t - off] : 0u;
        __syncthreads();
        s[t] += add;
        __syncthreads();
    }
    if (t < nb) bs[t] = s[t] - v;
    if (t == nb - 1) *total = s[t];
}

__global__ void scan_phase3_kernel(const uint32_t* __restrict__ bm,
                                   const uint32_t* __restrict__ bs,
                                   uint32_t* __restrict__ wp) {
    __shared__ uint32_t s[256];
    int t = threadIdx.x;
    int base = blockIdx.x * 1024 + t * 4;
    uint32_t p0 = __popc(bm[base]),   p1 = __popc(bm[base+1]);
    uint32_t p2 = __popc(bm[base+2]), p3 = __popc(bm[base+3]);
    uint32_t sum = p0 + p1 + p2 + p3;
    s[t] = sum;
    __syncthreads();
    for (int off = 1; off < 256; off <<= 1) {
        uint32_t add = (t >= off) ? s[t - off] : 0u;
        __syncthreads();
        s[t] += add;
        __syncthreads();
    }
    uint32_t ex = s[t] - sum + bs[blockIdx.x];
    wp[base]   = ex;
    wp[base+1] = ex + p0;
    wp[base+2] = ex + p0 + p1;
    wp[base+3] = ex + p0 + p1 + p2;
}

// --------------- value prefix scan (guarded, for counts -> starts) ---------------
__global__ void vscan_phase1_kernel(const uint32_t* __restrict__ v,
                                    uint32_t* __restrict__ bs, int n) {
    __shared__ uint32_t s[256];
    int t = threadIdx.x;
    int base = blockIdx.x * 1024 + t * 4;
    uint32_t sum = 0;
    #pragma unroll
    for (int j = 0; j < 4; j++) sum += (base + j < n) ? v[base + j] : 0u;
    s[t] = sum;
    __syncthreads();
    for (int off = 128; off > 0; off >>= 1) {
        if (t < off) s[t] += s[t + off];
        __syncthreads();
    }
    if (t == 0) bs[blockIdx.x] = s[0];
}

__global__ void vscan_phase3_kernel(const uint32_t* __restrict__ v,
                                    const uint32_t* __restrict__ bs,
                                    uint32_t* __restrict__ ex_out, int n) {
    __shared__ uint32_t s[256];
    int t = threadIdx.x;
    int base = blockIdx.x * 1024 + t * 4;
    uint32_t p[4];
    #pragma unroll
    for (int j = 0; j < 4; j++) p[j] = (base + j < n) ? v[base + j] : 0u;
    uint32_t sum = p[0] + p[1] + p[2] + p[3];
    s[t] = sum;
    __syncthreads();
    for (int off = 1; off < 256; off <<= 1) {
        uint32_t add = (t >= off) ? s[t - off] : 0u;
        __syncthreads();
        s[t] += add;
        __syncthreads();
    }
    uint32_t e = s[t] - sum + bs[blockIdx.x];
    #pragma unroll
    for (int j = 0; j < 4; j++) {
        if (base + j < n) ex_out[base + j] = e;
        e += p[j];
    }
}

// Wt[n][k] = bf16(W[k][n])  (B^T in bf16, 32 KB, L2-resident for the GEMM)
__global__ void convert_w_kernel(const float* __restrict__ W,
                                 ushort* __restrict__ Wt) {
    int id = blockIdx.x * blockDim.x + threadIdx.x;  // 0..16383
    int n = id >> 7, k = id & 127;
    Wt[id] = (ushort)f2bf1(W[k * C + n]);
}

// per input row: rank1 -> counts + rank cache
__global__ void count_kernel(const int* __restrict__ coords,
                             const uint32_t* __restrict__ bm1,
                             const uint32_t* __restrict__ wp1,
                             uint32_t* __restrict__ counts,
                             uint32_t* __restrict__ rank1_arr, int M) {
    int i = blockIdx.x * blockDim.x + threadIdx.x;
    if (i >= M) return;
    int b = coords[4*i+0], z = coords[4*i+1], y = coords[4*i+2], x = coords[4*i+3];
    uint32_t k1 = ((uint32_t)(b>>1)<<23) | ((uint32_t)(z>>1)<<18) |
                  ((uint32_t)(y>>1)<<9)  | (uint32_t)(x>>1);
    uint32_t r1 = wp1[k1>>5] + __popc(bm1[k1>>5] & ((1u << (k1 & 31)) - 1u));
    rank1_arr[i] = r1;
    atomicAdd(&counts[r1], 1u);
}

// counting-sort scatter: perm[start1[r1] + slot] = i
__global__ void perm_kernel(const uint32_t* __restrict__ rank1_arr,
                            const uint32_t* __restrict__ start1,
                            uint32_t* __restrict__ cursor,
                            uint32_t* __restrict__ perm, int M) {
    int i = blockIdx.x * blockDim.x + threadIdx.x;
    if (i >= M) return;
    uint32_t r1 = rank1_arr[i];
    uint32_t slot = atomicAdd(&cursor[r1], 1u);
    perm[start1[r1] + slot] = i;
}

// ------- stage B: sweep bm1; per level-1 node compute parent rank2 + row counts -------
__global__ void childsum_kernel(const uint32_t* __restrict__ bm1,
                                const uint32_t* __restrict__ wp1,
                                const uint32_t* __restrict__ bm2,
                                const uint32_t* __restrict__ wp2,
                                const uint32_t* __restrict__ counts,
                                uint32_t* __restrict__ parent_r2,
                                uint32_t* __restrict__ rowcounts2, int nwords) {
    int w = blockIdx.x * blockDim.x + threadIdx.x;
    if (w >= nwords) return;
    uint32_t bits = bm1[w];
    if (!bits) return;
    uint32_t r1 = wp1[w];
    while (bits) {
        int bit = __ffs(bits) - 1;
        uint32_t k1 = ((uint32_t)w << 5) | (uint32_t)bit;
        uint32_t z1 = (k1 >> 18) & 31u, y1 = (k1 >> 9) & 511u, x1 = k1 & 511u;
        uint32_t k2 = ((z1 >> 1) << 16) | ((y1 >> 1) << 8) | (x1 >> 1);
        uint32_t word2 = bm2[k2 >> 5];
        uint32_t r2 = wp2[k2 >> 5] + __popc(word2 & ((1u << (k2 & 31)) - 1u));
        parent_r2[r1] = r2;
        atomicAdd(&rowcounts2[r2], counts[r1]);
        r1++;
        bits &= bits - 1;
    }
}

// ------- stage C: flatten input rows into perm_f grouped by r2, group starts flagged -------
__global__ void flatten_kernel(const uint32_t* __restrict__ parent_r2,
                               const uint32_t* __restrict__ counts,
                               const uint32_t* __restrict__ start1,
                               const uint32_t* __restrict__ rowstart2,
                               uint32_t* __restrict__ cursor2,
                               const uint32_t* __restrict__ perm,
                               uint32_t* __restrict__ perm_f,
                               const uint32_t* __restrict__ totals, int M) {
    int i = blockIdx.x * blockDim.x + threadIdx.x;
    if (i >= M) return;
    uint32_t U1 = totals[0];
    if ((uint32_t)i >= U1) return;
    uint32_t r2 = parent_r2[i];
    uint32_t cnt = counts[i];
    uint32_t base = atomicAdd(&cursor2[r2], cnt);
    uint32_t dst = rowstart2[r2] + base;
    uint32_t s = start1[i];
    perm_f[dst] = perm[s] | 0x80000000u;               // flag = start of relu group
    for (uint32_t q = 1; q < cnt; ++q) perm_f[dst + q] = perm[s + q];
}

// ---------------- bf16 MFMA GEMM: g = bf16( relu(X) @ W0 ) ----------------
// block = 64 rows x 128 cols, 4 waves (16 rows each), K=128 in registers.
#define LDW 136  // f32 stride of Ol tile (pad so 4-row-apart stores hit distinct banks)
__global__ __launch_bounds__(256) void gemm_kernel(
    const float* __restrict__ X, const ushort* __restrict__ Wt,
    ushort* __restrict__ g, int M) {
    __shared__ __align__(16) char smem[64 * LDW * 4];   // 34.8 KB union
    float* Ol = (float*)smem;                           // phase 2: [64][LDW] f32
    const int t = threadIdx.x;
    const int row0 = blockIdx.x * 64;
    // phase 1: stage relu(X) as bf16 into Al[64][128] (XOR-swizzled 16B units)
    for (int it = 0; it < 8; ++it) {
        int fid = t + 256 * it;          // 0..2047
        int r = fid >> 5, c4 = fid & 31; // row, float4-col
        float4 v = ((const float4*)X)[(size_t)(row0 + r) * 32 + c4];
        uint32_t lo = f2bf1(fmaxf(v.x, 0.f)) | (f2bf1(fmaxf(v.y, 0.f)) << 16);
        uint32_t hi = f2bf1(fmaxf(v.z, 0.f)) | (f2bf1(fmaxf(v.w, 0.f)) << 16);
        int byte = r * 256 + ((c4 * 8) ^ ((r & 7) << 4));
        *(uint2*)(smem + byte) = make_uint2(lo, hi);
    }
    __syncthreads();
    const int w = t >> 6, l = t & 63;
    const int lrow = 16 * w + (l & 15);      // A-fragment row
    const int kb16 = (l >> 4) * 16;          // byte offset of this lane's 8-bf16 group
    bf16x8 af[4];
    #pragma unroll
    for (int ks = 0; ks < 4; ++ks) {
        int byte = lrow * 256 + ((ks * 64 + kb16) ^ ((lrow & 7) << 4));
        af[ks] = *(const bf16x8*)(smem + byte);
    }
    f32x4 acc[8];
    #pragma unroll
    for (int n = 0; n < 8; n++) acc[n] = (f32x4){0.f, 0.f, 0.f, 0.f};
    const int bcol = l & 15;
    const int bk = (l >> 4) * 8;
    #pragma unroll
    for (int n = 0; n < 8; n++) {
        bf16x8 bfr[4];
        #pragma unroll
        for (int ks = 0; ks < 4; ++ks)
            bfr[ks] = *(const bf16x8*)&Wt[(size_t)(16 * n + bcol) * 128 + ks * 32 + bk];
        #pragma unroll
        for (int ks = 0; ks < 4; ++ks)
            acc[n] = __builtin_amdgcn_mfma_f32_16x16x32_bf16(af[ks], bfr[ks], acc[n], 0, 0, 0);
    }
    __syncthreads();   // all waves done reading Al -> reuse smem as Ol
    #pragma unroll
    for (int n = 0; n < 8; n++)
        #pragma unroll
        for (int r = 0; r < 4; r++)
            Ol[(16 * w + 4 * (l >> 4) + r) * LDW + 16 * n + (l & 15)] = acc[n][r];
    __syncthreads();
    // phase 3: coalesced bf16 stores of g  (row = 32 uint2 of 8 bytes)
    for (int it = 0; it < 8; ++it) {
        int fid = t + 256 * it;
        int r = fid >> 5, c4 = fid & 31;
        float4 v = *(const float4*)&Ol[r * LDW + c4 * 4];
        uint32_t lo = f2bf1(v.x) | (f2bf1(v.y) << 16);
        uint32_t hi = f2bf1(v.z) | (f2bf1(v.w) << 16);
        ((uint2*)g)[(size_t)(row0 + r) * 32 + c4] = make_uint2(lo, hi);
    }
}

// ---------------- flattened gather: out[j] = sum_groups relu(sum_rows g) -------------
// one wave per output row; row list is precomputed (perm_f), group starts flagged bit31
__global__ __launch_bounds__(256) void gather2_kernel(
    const uint32_t* __restrict__ rowstart2, const uint32_t* __restrict__ rowcounts2,
    const uint32_t* __restrict__ perm_f, const ushort* __restrict__ g,
    float* __restrict__ out, int M) {
    int wid = (blockIdx.x * 256 + threadIdx.x) >> 6;
    wid = __builtin_amdgcn_readfirstlane(wid);         // force wave-uniform SGPR
    int lane = threadIdx.x & 63;
    if (wid >= M) return;
    const uint32_t* G = (const uint32_t*)g;
    float accx = 0.f, accy = 0.f;
    uint32_t n = rowcounts2[wid];
    if (n) {
        uint32_t s = rowstart2[wid];
        // one coalesced load grabs up to 64 row entries for the whole wave
        uint32_t ev = (lane < (int)n) ? perm_f[s + lane] : 0u;
        float sx = 0.f, sy = 0.f;
        uint32_t ecur = (uint32_t)__shfl((int)ev, 0);
        uint32_t pk = G[(size_t)(ecur & 0x7FFFFFFFu) * 64 + lane];
        for (uint32_t q = 1; q < n; ++q) {
            uint32_t en = (q < 64u) ? (uint32_t)__shfl((int)ev, (int)q)
                                    : perm_f[s + q];
            // issue next row's load before consuming current (keeps 2 loads in flight)
            uint32_t pkn = G[(size_t)(en & 0x7FFFFFFFu) * 64 + lane];
            sx += __uint_as_float(pk << 16);
            sy += __uint_as_float(pk & 0xFFFF0000u);
            if (en >> 31) {                            // new relu group begins at row q
                accx += fmaxf(sx, 0.f); accy += fmaxf(sy, 0.f);
                sx = 0.f; sy = 0.f;
            }
            pk = pkn;
        }
        sx += __uint_as_float(pk << 16);
        sy += __uint_as_float(pk & 0xFFFF0000u);
        accx += fmaxf(sx, 0.f);
        accy += fmaxf(sy, 0.f);
    }
    float2 o; o.x = accx; o.y = accy;
    ((float2*)out)[(size_t)wid * 64 + lane] = o;
}

extern "C" void kernel_launch(void* const* d_in, const int* in_sizes, int n_in,
                              void* d_out, int out_size, void* d_ws, size_t ws_size,
                              hipStream_t stream) {
    const float* X      = (const float*)d_in[0];
    const int*   coords = (const int*)d_in[1];
    const float* W      = (const float*)d_in[2];
    const int M = in_sizes[0] / C;               // 400000

    const int NW1 = 1 << 19;                     // 2^24-bit bitmap -> 524288 words
    const int NW2 = 1 << 15;                     // 2^20-bit bitmap -> 32768 words
    const int NB1 = NW1 / 1024;                  // 512
    const int NB2 = NW2 / 1024;                  // 32
    const int NBC = (M + 1023) / 1024;           // 391

    char* ws = (char*)d_ws;
    size_t off = 0;
    ushort*   g         = (ushort*)(ws + off);   off += (size_t)M * C * 2;   // 102.4 MB
    uint32_t* bm1       = (uint32_t*)(ws + off); off += (size_t)NW1 * 4;     // zeroed
    uint32_t* bm2       = (uint32_t*)(ws + off); off += (size_t)NW2 * 4;     // zeroed
    uint32_t* counts    = (uint32_t*)(ws + off); off += (size_t)M * 4;       // zeroed
    uint32_t* cursor    = (uint32_t*)(ws + off); off += (size_t)M * 4;       // zeroed
    uint32_t* rowcounts2= (uint32_t*)(ws + off); off += (size_t)M * 4;       // zeroed
    uint32_t* cursor2   = (uint32_t*)(ws + off); off += (size_t)M * 4;       // zeroed
    const size_t zero_off   = (size_t)M * C * 2;
    const size_t zero_bytes = off - zero_off;
    uint32_t* wp1       = (uint32_t*)(ws + off); off += (size_t)NW1 * 4;
    uint32_t* wp2       = (uint32_t*)(ws + off); off += (size_t)NW2 * 4;
    uint32_t* bs1       = (uint32_t*)(ws + off); off += 512 * 4;
    uint32_t* bs2       = (uint32_t*)(ws + off); off += 512 * 4;
    uint32_t* bsc       = (uint32_t*)(ws + off); off += 512 * 4;
    uint32_t* totals    = (uint32_t*)(ws + off); off += 4 * 4;
    uint32_t* start1    = (uint32_t*)(ws + off); off += (size_t)M * 4;
    uint32_t* rank1_arr = (uint32_t*)(ws + off); off += (size_t)M * 4;
    uint32_t* perm      = (uint32_t*)(ws + off); off += (size_t)M * 4;
    uint32_t* parent_r2 = (uint32_t*)(ws + off); off += (size_t)M * 4;
    uint32_t* rowstart2 = (uint32_t*)(ws + off); off += (size_t)M * 4;
    ushort*   Wt        = (ushort*)(ws + off);   off += (size_t)C * C * 2;
    uint32_t* perm_f    = rank1_arr;             // rank1_arr dead after perm_kernel

    hipMemsetAsync(ws + zero_off, 0, zero_bytes, stream);

    convert_w_kernel<<<64, 256, 0, stream>>>(W, Wt);
    mark_bits_kernel<<<(M + 255) / 256, 256, 0, stream>>>(coords, bm1, bm2, M);

    scan_phase1_kernel<<<NB1, 256, 0, stream>>>(bm1, bs1);
    scan_phase2_kernel<<<1, 512, 0, stream>>>(bs1, &totals[0], NB1);
    scan_phase3_kernel<<<NB1, 256, 0, stream>>>(bm1, bs1, wp1);

    scan_phase1_kernel<<<NB2, 256, 0, stream>>>(bm2, bs2);
    scan_phase2_kernel<<<1, 512, 0, stream>>>(bs2, &totals[1], NB2);
    scan_phase3_kernel<<<NB2, 256, 0, stream>>>(bm2, bs2, wp2);

    count_kernel<<<(M + 255) / 256, 256, 0, stream>>>(coords, bm1, wp1, counts, rank1_arr, M);

    vscan_phase1_kernel<<<NBC, 256, 0, stream>>>(counts, bsc, M);
    scan_phase2_kernel<<<1, 512, 0, stream>>>(bsc, &totals[2], NBC);
    vscan_phase3_kernel<<<NBC, 256, 0, stream>>>(counts, bsc, start1, M);

    perm_kernel<<<(M + 255) / 256, 256, 0, stream>>>(rank1_arr, start1, cursor, perm, M);

    // level-1 -> level-2 child aggregation metadata
    childsum_kernel<<<NW1 / 256, 256, 0, stream>>>(bm1, wp1, bm2, wp2, counts,
                                                   parent_r2, rowcounts2, NW1);

    vscan_phase1_kernel<<<NBC, 256, 0, stream>>>(rowcounts2, bsc, M);
    scan_phase2_kernel<<<1, 512, 0, stream>>>(bsc, &totals[3], NBC);
    vscan_phase3_kernel<<<NBC, 256, 0, stream>>>(rowcounts2, bsc, rowstart2, M);

    flatten_kernel<<<(M + 255) / 256, 256, 0, stream>>>(
        parent_r2, counts, start1, rowstart2, cursor2, perm, perm_f, totals, M);

    gemm_kernel<<<M / 64, 256, 0, stream>>>(X, Wt, g, M);

    gather2_kernel<<<(M + 3) / 4, 256, 0, stream>>>(
        rowstart2, rowcounts2, perm_f, g, (float*)d_out, M);
}

// Round 2
// 312.116 us; speedup vs baseline: 1.5628x; 1.2350x over previous
//
#include <hip/hip_runtime.h>
#include <stdint.h>

#define C 128

typedef __attribute__((ext_vector_type(8))) short bf16x8;
typedef __attribute__((ext_vector_type(4))) float f32x4;

// f32 -> bf16 bits, round-to-nearest-even
__device__ __forceinline__ uint32_t f2bf1(float f) {
    uint32_t u = __float_as_uint(f);
    return (u + 0x7FFFu + ((u >> 16) & 1u)) >> 16;
}

// ---------------- key packing ----------------
// level-1 key: b1(1)<<23 | z1(5)<<18 | y1(9)<<9 | x1(9); numeric order == lexicographic
// level-2 key: z2(4)<<16 | y2(8)<<8 | x2(8)               (b2 == 0 for all real rows)

__global__ void mark_bits_kernel(const int* __restrict__ coords,
                                 uint32_t* __restrict__ bm1,
                                 uint32_t* __restrict__ bm2, int M) {
    int i = blockIdx.x * blockDim.x + threadIdx.x;
    if (i >= M) return;
    int b = coords[4*i+0], z = coords[4*i+1], y = coords[4*i+2], x = coords[4*i+3];
    uint32_t k1 = ((uint32_t)(b>>1)<<23) | ((uint32_t)(z>>1)<<18) |
                  ((uint32_t)(y>>1)<<9)  | (uint32_t)(x>>1);
    uint32_t k2 = ((uint32_t)(z>>2)<<16) | ((uint32_t)(y>>2)<<8) | (uint32_t)(x>>2);
    atomicOr(&bm1[k1>>5], 1u << (k1 & 31));
    atomicOr(&bm2[k2>>5], 1u << (k2 & 31));
}

// --------------- popcount prefix scan over bitmap words (n multiple of 1024) ---------
__global__ void scan_phase1_kernel(const uint32_t* __restrict__ bm,
                                   uint32_t* __restrict__ bs) {
    __shared__ uint32_t s[256];
    int t = threadIdx.x;
    int base = blockIdx.x * 1024 + t * 4;
    uint32_t sum = __popc(bm[base]) + __popc(bm[base+1]) +
                   __popc(bm[base+2]) + __popc(bm[base+3]);
    s[t] = sum;
    __syncthreads();
    for (int off = 128; off > 0; off >>= 1) {
        if (t < off) s[t] += s[t + off];
        __syncthreads();
    }
    if (t == 0) bs[blockIdx.x] = s[0];
}

// single block exclusive scan of block sums (nb <= 512), writes total
__global__ void scan_phase2_kernel(uint32_t* __restrict__ bs,
                                   uint32_t* __restrict__ total, int nb) {
    __shared__ uint32_t s[512];
    int t = threadIdx.x;
    uint32_t v = (t < nb) ? bs[t] : 0u;
    s[t] = v;
    __syncthreads();
    for (int off = 1; off < 512; off <<= 1) {
        uint32_t add = (t >= off) ? s[t - off] : 0u;
        __syncthreads();
        s[t] += add;
        __syncthreads();
    }
    if (t < nb) bs[t] = s[t] - v;
    if (t == nb - 1) *total = s[t];
}

__global__ void scan_phase3_kernel(const uint32_t* __restrict__ bm,
                                   const uint32_t* __restrict__ bs,
                                   uint32_t* __restrict__ wp) {
    __shared__ uint32_t s[256];
    int t = threadIdx.x;
    int base = blockIdx.x * 1024 + t * 4;
    uint32_t p0 = __popc(bm[base]),   p1 = __popc(bm[base+1]);
    uint32_t p2 = __popc(bm[base+2]), p3 = __popc(bm[base+3]);
    uint32_t sum = p0 + p1 + p2 + p3;
    s[t] = sum;
    __syncthreads();
    for (int off = 1; off < 256; off <<= 1) {
        uint32_t add = (t >= off) ? s[t - off] : 0u;
        __syncthreads();
        s[t] += add;
        __syncthreads();
    }
    uint32_t ex = s[t] - sum + bs[blockIdx.x];
    wp[base]   = ex;
    wp[base+1] = ex + p0;
    wp[base+2] = ex + p0 + p1;
    wp[base+3] = ex + p0 + p1 + p2;
}

// --------------- value prefix scan (guarded, for counts -> starts) ---------------
__global__ void vscan_phase1_kernel(const uint32_t* __restrict__ v,
                                    uint32_t* __restrict__ bs, int n) {
    __shared__ uint32_t s[256];
    int t = threadIdx.x;
    int base = blockIdx.x * 1024 + t * 4;
    uint32_t sum = 0;
    #pragma unroll
    for (int j = 0; j < 4; j++) sum += (base + j < n) ? v[base + j] : 0u;
    s[t] = sum;
    __syncthreads();
    for (int off = 128; off > 0; off >>= 1) {
        if (t < off) s[t] += s[t + off];
        __syncthreads();
    }
    if (t == 0) bs[blockIdx.x] = s[0];
}

__global__ void vscan_phase3_kernel(const uint32_t* __restrict__ v,
                                    const uint32_t* __restrict__ bs,
                                    uint32_t* __restrict__ ex_out, int n) {
    __shared__ uint32_t s[256];
    int t = threadIdx.x;
    int base = blockIdx.x * 1024 + t * 4;
    uint32_t p[4];
    #pragma unroll
    for (int j = 0; j < 4; j++) p[j] = (base + j < n) ? v[base + j] : 0u;
    uint32_t sum = p[0] + p[1] + p[2] + p[3];
    s[t] = sum;
    __syncthreads();
    for (int off = 1; off < 256; off <<= 1) {
        uint32_t add = (t >= off) ? s[t - off] : 0u;
        __syncthreads();
        s[t] += add;
        __syncthreads();
    }
    uint32_t e = s[t] - sum + bs[blockIdx.x];
    #pragma unroll
    for (int j = 0; j < 4; j++) {
        if (base + j < n) ex_out[base + j] = e;
        e += p[j];
    }
}

// Wt[n][k] = bf16(W[k][n])  (B^T in bf16, 32 KB, L2-resident for the GEMM)
__global__ void convert_w_kernel(const float* __restrict__ W,
                                 ushort* __restrict__ Wt) {
    int id = blockIdx.x * blockDim.x + threadIdx.x;  // 0..16383
    int n = id >> 7, k = id & 127;
    Wt[id] = (ushort)f2bf1(W[k * C + n]);
}

// per input row: rank1 -> counts + rank cache
__global__ void count_kernel(const int* __restrict__ coords,
                             const uint32_t* __restrict__ bm1,
                             const uint32_t* __restrict__ wp1,
                             uint32_t* __restrict__ counts,
                             uint32_t* __restrict__ rank1_arr, int M) {
    int i = blockIdx.x * blockDim.x + threadIdx.x;
    if (i >= M) return;
    int b = coords[4*i+0], z = coords[4*i+1], y = coords[4*i+2], x = coords[4*i+3];
    uint32_t k1 = ((uint32_t)(b>>1)<<23) | ((uint32_t)(z>>1)<<18) |
                  ((uint32_t)(y>>1)<<9)  | (uint32_t)(x>>1);
    uint32_t r1 = wp1[k1>>5] + __popc(bm1[k1>>5] & ((1u << (k1 & 31)) - 1u));
    rank1_arr[i] = r1;
    atomicAdd(&counts[r1], 1u);
}

// counting-sort scatter: perm[start1[r1] + slot] = i
__global__ void perm_kernel(const uint32_t* __restrict__ rank1_arr,
                            const uint32_t* __restrict__ start1,
                            uint32_t* __restrict__ cursor,
                            uint32_t* __restrict__ perm, int M) {
    int i = blockIdx.x * blockDim.x + threadIdx.x;
    if (i >= M) return;
    uint32_t r1 = rank1_arr[i];
    uint32_t slot = atomicAdd(&cursor[r1], 1u);
    perm[start1[r1] + slot] = i;
}

// ------- stage B: sweep bm1; per level-1 node compute parent rank2 + row counts -------
__global__ void childsum_kernel(const uint32_t* __restrict__ bm1,
                                const uint32_t* __restrict__ wp1,
                                const uint32_t* __restrict__ bm2,
                                const uint32_t* __restrict__ wp2,
                                const uint32_t* __restrict__ counts,
                                uint32_t* __restrict__ parent_r2,
                                uint32_t* __restrict__ rowcounts2, int nwords) {
    int w = blockIdx.x * blockDim.x + threadIdx.x;
    if (w >= nwords) return;
    uint32_t bits = bm1[w];
    if (!bits) return;
    uint32_t r1 = wp1[w];
    while (bits) {
        int bit = __ffs(bits) - 1;
        uint32_t k1 = ((uint32_t)w << 5) | (uint32_t)bit;
        uint32_t z1 = (k1 >> 18) & 31u, y1 = (k1 >> 9) & 511u, x1 = k1 & 511u;
        uint32_t k2 = ((z1 >> 1) << 16) | ((y1 >> 1) << 8) | (x1 >> 1);
        uint32_t word2 = bm2[k2 >> 5];
        uint32_t r2 = wp2[k2 >> 5] + __popc(word2 & ((1u << (k2 & 31)) - 1u));
        parent_r2[r1] = r2;
        atomicAdd(&rowcounts2[r2], counts[r1]);
        r1++;
        bits &= bits - 1;
    }
}

// ------- stage C: flatten input rows into perm_f grouped by r2, group starts flagged -------
__global__ void flatten_kernel(const uint32_t* __restrict__ parent_r2,
                               const uint32_t* __restrict__ counts,
                               const uint32_t* __restrict__ start1,
                               const uint32_t* __restrict__ rowstart2,
                               uint32_t* __restrict__ cursor2,
                               const uint32_t* __restrict__ perm,
                               uint32_t* __restrict__ perm_f,
                               const uint32_t* __restrict__ totals, int M) {
    int i = blockIdx.x * blockDim.x + threadIdx.x;
    if (i >= M) return;
    uint32_t U1 = totals[0];
    if ((uint32_t)i >= U1) return;
    uint32_t r2 = parent_r2[i];
    uint32_t cnt = counts[i];
    uint32_t base = atomicAdd(&cursor2[r2], cnt);
    uint32_t dst = rowstart2[r2] + base;
    uint32_t s = start1[i];
    perm_f[dst] = perm[s] | 0x80000000u;               // flag = start of relu group
    for (uint32_t q = 1; q < cnt; ++q) perm_f[dst + q] = perm[s + q];
}

// ---------------- bf16 MFMA GEMM: g = bf16( relu(X) @ W0 ) ----------------
// Barrier-free: one wave = one 16-row tile, grid-stride with 1-deep register
// prefetch. Wt staged once per block into LDS in fragment-major layout
// [ks][kg][n][m] x 16B so every B-fragment is a conflict-free ds_read_b128
// with a compile-time immediate offset. Output stored directly from acc
// fragments (same wave writes each row's full 256 B -> L2 merges lines).
__global__ __launch_bounds__(256) void gemm_kernel(
    const float* __restrict__ X, const ushort* __restrict__ Wt,
    ushort* __restrict__ g, int M) {
    __shared__ __align__(16) ushort wlds[16384];       // 32 KB
    const int t = threadIdx.x;
    {
        // stage Wt: src chunk (row=16n+m, kc) -> dst [ks=kc>>2][kg=kc&3][n][m]
        int sm = t & 15, kc = t >> 4;                  // kc 0..15
        const char* src = (const char*)Wt;
        char* dst = (char*)wlds;
        #pragma unroll
        for (int n = 0; n < 8; ++n) {
            uint4 v = *(const uint4*)(src + n*4096 + sm*256 + kc*16);
            *(uint4*)(dst + (kc>>2)*8192 + (kc&3)*2048 + n*256 + sm*16) = v;
        }
    }
    __syncthreads();                                   // only barrier in kernel
    const int l = t & 63;
    const int lm = l & 15, kg = l >> 4;                // A-frag row / k-group
    const int ntiles = M >> 4;
    const int nw = gridDim.x * 4;
    int tile = blockIdx.x * 4 + (t >> 6);
    const char* wbase = (const char*)wlds + kg*2048 + lm*16;

    float4 pf[8];
    if (tile < ntiles) {
        const char* xb = (const char*)X + ((size_t)tile*16 + lm)*512 + kg*32;
        #pragma unroll
        for (int ks = 0; ks < 4; ++ks) {
            pf[2*ks]   = *(const float4*)(xb + ks*128);
            pf[2*ks+1] = *(const float4*)(xb + ks*128 + 16);
        }
    }
    while (tile < ntiles) {
        const int next = tile + nw;
        // convert current tile's X rows -> A fragments (relu + bf16 pack)
        bf16x8 af[4];
        #pragma unroll
        for (int ks = 0; ks < 4; ++ks) {
            float4 a = pf[2*ks], b = pf[2*ks+1];
            union { uint32_t u[4]; bf16x8 v; } cv;
            cv.u[0] = f2bf1(fmaxf(a.x,0.f)) | (f2bf1(fmaxf(a.y,0.f)) << 16);
            cv.u[1] = f2bf1(fmaxf(a.z,0.f)) | (f2bf1(fmaxf(a.w,0.f)) << 16);
            cv.u[2] = f2bf1(fmaxf(b.x,0.f)) | (f2bf1(fmaxf(b.y,0.f)) << 16);
            cv.u[3] = f2bf1(fmaxf(b.z,0.f)) | (f2bf1(fmaxf(b.w,0.f)) << 16);
            af[ks] = cv.v;
        }
        // issue next tile's loads now; they fly under the MFMA + stores below
        if (next < ntiles) {
            const char* xb = (const char*)X + ((size_t)next*16 + lm)*512 + kg*32;
            #pragma unroll
            for (int ks = 0; ks < 4; ++ks) {
                pf[2*ks]   = *(const float4*)(xb + ks*128);
                pf[2*ks+1] = *(const float4*)(xb + ks*128 + 16);
            }
        }
        ushort* grow = g + (size_t)((size_t)tile*16 + 4*kg)*128 + lm;
        #pragma unroll
        for (int n = 0; n < 8; ++n) {
            bf16x8 b0 = *(const bf16x8*)(wbase + n*256);
            bf16x8 b1 = *(const bf16x8*)(wbase + n*256 + 8192);
            bf16x8 b2 = *(const bf16x8*)(wbase + n*256 + 16384);
            bf16x8 b3 = *(const bf16x8*)(wbase + n*256 + 24576);
            f32x4 acc = (f32x4){0.f, 0.f, 0.f, 0.f};
            acc = __builtin_amdgcn_mfma_f32_16x16x32_bf16(af[0], b0, acc, 0, 0, 0);
            acc = __builtin_amdgcn_mfma_f32_16x16x32_bf16(af[1], b1, acc, 0, 0, 0);
            acc = __builtin_amdgcn_mfma_f32_16x16x32_bf16(af[2], b2, acc, 0, 0, 0);
            acc = __builtin_amdgcn_mfma_f32_16x16x32_bf16(af[3], b3, acc, 0, 0, 0);
            #pragma unroll
            for (int r = 0; r < 4; ++r)
                grow[(size_t)r*128 + 16*n] = (ushort)f2bf1(acc[r]);
        }
        tile = next;
    }
}

// ---------------- flattened gather: out[j] = sum_groups relu(sum_rows g) -------------
// one wave per output row; row list is precomputed (perm_f), group starts flagged bit31
__global__ __launch_bounds__(256) void gather2_kernel(
    const uint32_t* __restrict__ rowstart2, const uint32_t* __restrict__ rowcounts2,
    const uint32_t* __restrict__ perm_f, const ushort* __restrict__ g,
    float* __restrict__ out, int M) {
    int wid = (blockIdx.x * 256 + threadIdx.x) >> 6;
    wid = __builtin_amdgcn_readfirstlane(wid);         // force wave-uniform SGPR
    int lane = threadIdx.x & 63;
    if (wid >= M) return;
    const uint32_t* G = (const uint32_t*)g;
    float accx = 0.f, accy = 0.f;
    uint32_t n = rowcounts2[wid];
    if (n) {
        uint32_t s = rowstart2[wid];
        // one coalesced load grabs up to 64 row entries for the whole wave
        uint32_t ev = (lane < (int)n) ? perm_f[s + lane] : 0u;
        float sx = 0.f, sy = 0.f;
        uint32_t ecur = (uint32_t)__shfl((int)ev, 0);
        uint32_t pk = G[(size_t)(ecur & 0x7FFFFFFFu) * 64 + lane];
        for (uint32_t q = 1; q < n; ++q) {
            uint32_t en = (q < 64u) ? (uint32_t)__shfl((int)ev, (int)q)
                                    : perm_f[s + q];
            // issue next row's load before consuming current (keeps 2 loads in flight)
            uint32_t pkn = G[(size_t)(en & 0x7FFFFFFFu) * 64 + lane];
            sx += __uint_as_float(pk << 16);
            sy += __uint_as_float(pk & 0xFFFF0000u);
            if (en >> 31) {                            // new relu group begins at row q
                accx += fmaxf(sx, 0.f); accy += fmaxf(sy, 0.f);
                sx = 0.f; sy = 0.f;
            }
            pk = pkn;
        }
        sx += __uint_as_float(pk << 16);
        sy += __uint_as_float(pk & 0xFFFF0000u);
        accx += fmaxf(sx, 0.f);
        accy += fmaxf(sy, 0.f);
    }
    float2 o; o.x = accx; o.y = accy;
    ((float2*)out)[(size_t)wid * 64 + lane] = o;
}

extern "C" void kernel_launch(void* const* d_in, const int* in_sizes, int n_in,
                              void* d_out, int out_size, void* d_ws, size_t ws_size,
                              hipStream_t stream) {
    const float* X      = (const float*)d_in[0];
    const int*   coords = (const int*)d_in[1];
    const float* W      = (const float*)d_in[2];
    const int M = in_sizes[0] / C;               // 400000

    const int NW1 = 1 << 19;                     // 2^24-bit bitmap -> 524288 words
    const int NW2 = 1 << 15;                     // 2^20-bit bitmap -> 32768 words
    const int NB1 = NW1 / 1024;                  // 512
    const int NB2 = NW2 / 1024;                  // 32
    const int NBC = (M + 1023) / 1024;           // 391

    char* ws = (char*)d_ws;
    size_t off = 0;
    ushort*   g         = (ushort*)(ws + off);   off += (size_t)M * C * 2;   // 102.4 MB
    uint32_t* bm1       = (uint32_t*)(ws + off); off += (size_t)NW1 * 4;     // zeroed
    uint32_t* bm2       = (uint32_t*)(ws + off); off += (size_t)NW2 * 4;     // zeroed
    uint32_t* counts    = (uint32_t*)(ws + off); off += (size_t)M * 4;       // zeroed
    uint32_t* cursor    = (uint32_t*)(ws + off); off += (size_t)M * 4;       // zeroed
    uint32_t* rowcounts2= (uint32_t*)(ws + off); off += (size_t)M * 4;       // zeroed
    uint32_t* cursor2   = (uint32_t*)(ws + off); off += (size_t)M * 4;       // zeroed
    const size_t zero_off   = (size_t)M * C * 2;
    const size_t zero_bytes = off - zero_off;
    uint32_t* wp1       = (uint32_t*)(ws + off); off += (size_t)NW1 * 4;
    uint32_t* wp2       = (uint32_t*)(ws + off); off += (size_t)NW2 * 4;
    uint32_t* bs1       = (uint32_t*)(ws + off); off += 512 * 4;
    uint32_t* bs2       = (uint32_t*)(ws + off); off += 512 * 4;
    uint32_t* bsc       = (uint32_t*)(ws + off); off += 512 * 4;
    uint32_t* totals    = (uint32_t*)(ws + off); off += 4 * 4;
    uint32_t* start1    = (uint32_t*)(ws + off); off += (size_t)M * 4;
    uint32_t* rank1_arr = (uint32_t*)(ws + off); off += (size_t)M * 4;
    uint32_t* perm      = (uint32_t*)(ws + off); off += (size_t)M * 4;
    uint32_t* parent_r2 = (uint32_t*)(ws + off); off += (size_t)M * 4;
    uint32_t* rowstart2 = (uint32_t*)(ws + off); off += (size_t)M * 4;
    ushort*   Wt        = (ushort*)(ws + off);   off += (size_t)C * C * 2;
    uint32_t* perm_f    = rank1_arr;             // rank1_arr dead after perm_kernel

    hipMemsetAsync(ws + zero_off, 0, zero_bytes, stream);

    convert_w_kernel<<<64, 256, 0, stream>>>(W, Wt);
    mark_bits_kernel<<<(M + 255) / 256, 256, 0, stream>>>(coords, bm1, bm2, M);

    scan_phase1_kernel<<<NB1, 256, 0, stream>>>(bm1, bs1);
    scan_phase2_kernel<<<1, 512, 0, stream>>>(bs1, &totals[0], NB1);
    scan_phase3_kernel<<<NB1, 256, 0, stream>>>(bm1, bs1, wp1);

    scan_phase1_kernel<<<NB2, 256, 0, stream>>>(bm2, bs2);
    scan_phase2_kernel<<<1, 512, 0, stream>>>(bs2, &totals[1], NB2);
    scan_phase3_kernel<<<NB2, 256, 0, stream>>>(bm2, bs2, wp2);

    count_kernel<<<(M + 255) / 256, 256, 0, stream>>>(coords, bm1, wp1, counts, rank1_arr, M);

    vscan_phase1_kernel<<<NBC, 256, 0, stream>>>(counts, bsc, M);
    scan_phase2_kernel<<<1, 512, 0, stream>>>(bsc, &totals[2], NBC);
    vscan_phase3_kernel<<<NBC, 256, 0, stream>>>(counts, bsc, start1, M);

    perm_kernel<<<(M + 255) / 256, 256, 0, stream>>>(rank1_arr, start1, cursor, perm, M);

    // level-1 -> level-2 child aggregation metadata
    childsum_kernel<<<NW1 / 256, 256, 0, stream>>>(bm1, wp1, bm2, wp2, counts,
                                                   parent_r2, rowcounts2, NW1);

    vscan_phase1_kernel<<<NBC, 256, 0, stream>>>(rowcounts2, bsc, M);
    scan_phase2_kernel<<<1, 512, 0, stream>>>(bsc, &totals[3], NBC);
    vscan_phase3_kernel<<<NBC, 256, 0, stream>>>(rowcounts2, bsc, rowstart2, M);

    flatten_kernel<<<(M + 255) / 256, 256, 0, stream>>>(
        parent_r2, counts, start1, rowstart2, cursor2, perm, perm_f, totals, M);

    gemm_kernel<<<1024, 256, 0, stream>>>(X, Wt, g, M);

    gather2_kernel<<<(M + 3) / 4, 256, 0, stream>>>(
        rowstart2, rowcounts2, perm_f, g, (float*)d_out, M);
}

// Round 3
// 294.829 us; speedup vs baseline: 1.6544x; 1.0586x over previous
//
#include <hip/hip_runtime.h>
#include <stdint.h>

#define C 128

typedef __attribute__((ext_vector_type(8))) short bf16x8;
typedef __attribute__((ext_vector_type(4))) float f32x4;

// f32 -> bf16 bits, round-to-nearest-even
__device__ __forceinline__ uint32_t f2bf1(float f) {
    uint32_t u = __float_as_uint(f);
    return (u + 0x7FFFu + ((u >> 16) & 1u)) >> 16;
}

// ---------------- key packing ----------------
// level-1 key: b1(1)<<23 | z1(5)<<18 | y1(9)<<9 | x1(9); numeric order == lexicographic
// level-2 key: z2(4)<<16 | y2(8)<<8 | x2(8)               (b2 == 0 for all real rows)

// ---- merged: mark bitmap bits (blocks 0..781) + convert W -> Wt bf16 (blocks 782..813)
__global__ __launch_bounds__(512) void markconv_kernel(
    const int* __restrict__ coords, uint32_t* __restrict__ bm1,
    uint32_t* __restrict__ bm2, const float* __restrict__ W,
    ushort* __restrict__ Wt, int M, int nmark) {
    int b = blockIdx.x, t = threadIdx.x;
    if (b < nmark) {
        int i = b * 512 + t;
        if (i >= M) return;
        int bb = coords[4*i+0], z = coords[4*i+1], y = coords[4*i+2], x = coords[4*i+3];
        uint32_t k1 = ((uint32_t)(bb>>1)<<23) | ((uint32_t)(z>>1)<<18) |
                      ((uint32_t)(y>>1)<<9)  | (uint32_t)(x>>1);
        uint32_t k2 = ((uint32_t)(z>>2)<<16) | ((uint32_t)(y>>2)<<8) | (uint32_t)(x>>2);
        atomicOr(&bm1[k1>>5], 1u << (k1 & 31));
        atomicOr(&bm2[k2>>5], 1u << (k2 & 31));
    } else {
        int id = (b - nmark) * 512 + t;                // 0..16383
        int n = id >> 7, k = id & 127;
        Wt[id] = (ushort)f2bf1(W[k * C + n]);
    }
}

// ---------------- shared device helpers (512-thread scan primitives) ----------------
__device__ __forceinline__ void bscan1_512(const uint32_t* bm, uint32_t* bs,
                                           int blk, uint32_t* s, int t) {
    int base = blk * 1024 + t * 2;
    uint32_t sum = __popc(bm[base]) + __popc(bm[base+1]);
    s[t] = sum;
    __syncthreads();
    for (int off = 256; off > 0; off >>= 1) {
        if (t < off) s[t] += s[t + off];
        __syncthreads();
    }
    if (t == 0) bs[blk] = s[0];
}

__device__ __forceinline__ void bscan3_512(const uint32_t* bm, const uint32_t* bs,
                                           uint32_t* wp, int blk, uint32_t* s, int t) {
    int base = blk * 1024 + t * 2;
    uint32_t p0 = __popc(bm[base]), p1 = __popc(bm[base+1]);
    uint32_t sum = p0 + p1;
    s[t] = sum;
    __syncthreads();
    for (int off = 1; off < 512; off <<= 1) {
        uint32_t add = (t >= off) ? s[t - off] : 0u;
        __syncthreads();
        s[t] += add;
        __syncthreads();
    }
    uint32_t ex = s[t] - sum + bs[blk];
    wp[base]   = ex;
    wp[base+1] = ex + p0;
}

// single-block exclusive scan of nb<=512 block sums, in place, writes total
__device__ __forceinline__ void blksum_scan_512(uint32_t* bs, uint32_t* total,
                                                int nb, uint32_t* s, int t) {
    uint32_t v = (t < nb) ? bs[t] : 0u;
    s[t] = v;
    __syncthreads();
    for (int off = 1; off < 512; off <<= 1) {
        uint32_t add = (t >= off) ? s[t - off] : 0u;
        __syncthreads();
        s[t] += add;
        __syncthreads();
    }
    if (t < nb) bs[t] = s[t] - v;
    if (t == nb - 1) *total = s[t];
}

__device__ __forceinline__ void vscan1_512(const uint32_t* v, uint32_t* bs,
                                           int blk, int n, uint32_t* s, int t) {
    int base = blk * 1024 + t * 2;
    uint32_t sum = 0;
    if (base     < n) sum += v[base];
    if (base + 1 < n) sum += v[base+1];
    s[t] = sum;
    __syncthreads();
    for (int off = 256; off > 0; off >>= 1) {
        if (t < off) s[t] += s[t + off];
        __syncthreads();
    }
    if (t == 0) bs[blk] = s[0];
}

__device__ __forceinline__ void vscan3_512(const uint32_t* v, const uint32_t* bs,
                                           uint32_t* ex_out, int blk, int n,
                                           uint32_t* s, int t) {
    int base = blk * 1024 + t * 2;
    uint32_t p0 = (base     < n) ? v[base]   : 0u;
    uint32_t p1 = (base + 1 < n) ? v[base+1] : 0u;
    uint32_t sum = p0 + p1;
    s[t] = sum;
    __syncthreads();
    for (int off = 1; off < 512; off <<= 1) {
        uint32_t add = (t >= off) ? s[t - off] : 0u;
        __syncthreads();
        s[t] += add;
        __syncthreads();
    }
    uint32_t e = s[t] - sum + bs[blk];
    if (base     < n) ex_out[base]   = e;
    if (base + 1 < n) ex_out[base+1] = e + p0;
}

// ---- merged bitmap scan phases: blocks [0,512) -> bm1, [512,544) -> bm2 ----
__global__ __launch_bounds__(512) void mscan1_kernel(
    const uint32_t* __restrict__ bm1, uint32_t* __restrict__ bs1,
    const uint32_t* __restrict__ bm2, uint32_t* __restrict__ bs2) {
    __shared__ uint32_t s[512];
    int b = blockIdx.x, t = threadIdx.x;
    if (b < 512) bscan1_512(bm1, bs1, b, s, t);
    else         bscan1_512(bm2, bs2, b - 512, s, t);
}

__global__ __launch_bounds__(512) void mscan2_kernel(
    uint32_t* __restrict__ bs1, uint32_t* __restrict__ bs2,
    uint32_t* __restrict__ totals) {
    __shared__ uint32_t s[512];
    int t = threadIdx.x;
    if (blockIdx.x == 0) blksum_scan_512(bs1, &totals[0], 512, s, t);
    else                 blksum_scan_512(bs2, &totals[1], 32,  s, t);
}

__global__ __launch_bounds__(512) void mscan3_kernel(
    const uint32_t* __restrict__ bm1, const uint32_t* __restrict__ bs1,
    uint32_t* __restrict__ wp1,
    const uint32_t* __restrict__ bm2, const uint32_t* __restrict__ bs2,
    uint32_t* __restrict__ wp2) {
    __shared__ uint32_t s[512];
    int b = blockIdx.x, t = threadIdx.x;
    if (b < 512) bscan3_512(bm1, bs1, wp1, b, s, t);
    else         bscan3_512(bm2, bs2, wp2, b - 512, s, t);
}

// per input row: rank1 -> counts + rank cache
__global__ __launch_bounds__(512) void count_kernel(
    const int* __restrict__ coords, const uint32_t* __restrict__ bm1,
    const uint32_t* __restrict__ wp1, uint32_t* __restrict__ counts,
    uint32_t* __restrict__ rank1_arr, int M) {
    int i = blockIdx.x * 512 + threadIdx.x;
    if (i >= M) return;
    int b = coords[4*i+0], z = coords[4*i+1], y = coords[4*i+2], x = coords[4*i+3];
    uint32_t k1 = ((uint32_t)(b>>1)<<23) | ((uint32_t)(z>>1)<<18) |
                  ((uint32_t)(y>>1)<<9)  | (uint32_t)(x>>1);
    uint32_t r1 = wp1[k1>>5] + __popc(bm1[k1>>5] & ((1u << (k1 & 31)) - 1u));
    rank1_arr[i] = r1;
    atomicAdd(&counts[r1], 1u);
}

// ---- MK1: blocks [0,nbc) vscan1(counts) ; [nbc, nbc+1024) childsum over bm1 words ----
__global__ __launch_bounds__(512) void mk1_kernel(
    const uint32_t* __restrict__ counts, uint32_t* __restrict__ bsc,
    const uint32_t* __restrict__ bm1, const uint32_t* __restrict__ wp1,
    const uint32_t* __restrict__ bm2, const uint32_t* __restrict__ wp2,
    uint32_t* __restrict__ parent_r2, uint32_t* __restrict__ rowcounts2,
    int M, int nbc, int nwords) {
    int b = blockIdx.x, t = threadIdx.x;
    if (b < nbc) {
        __shared__ uint32_t s[512];
        vscan1_512(counts, bsc, b, M, s, t);
        return;
    }
    int w = (b - nbc) * 512 + t;
    if (w >= nwords) return;
    uint32_t bits = bm1[w];
    if (!bits) return;
    uint32_t r1 = wp1[w];
    while (bits) {
        int bit = __ffs(bits) - 1;
        uint32_t k1 = ((uint32_t)w << 5) | (uint32_t)bit;
        uint32_t z1 = (k1 >> 18) & 31u, y1 = (k1 >> 9) & 511u, x1 = k1 & 511u;
        uint32_t k2 = ((z1 >> 1) << 16) | ((y1 >> 1) << 8) | (x1 >> 1);
        uint32_t word2 = bm2[k2 >> 5];
        uint32_t r2 = wp2[k2 >> 5] + __popc(word2 & ((1u << (k2 & 31)) - 1u));
        parent_r2[r1] = r2;
        atomicAdd(&rowcounts2[r2], counts[r1]);
        r1++;
        bits &= bits - 1;
    }
}

// ---- MK2: block 0 scan2(bsc->totals[2]) ; blocks [1,1+nbc) vscan1(rowcounts2) ----
__global__ __launch_bounds__(512) void mk2_kernel(
    uint32_t* __restrict__ bsc, uint32_t* __restrict__ totals,
    const uint32_t* __restrict__ rowcounts2, uint32_t* __restrict__ bsc2,
    int M, int nbc) {
    __shared__ uint32_t s[512];
    int b = blockIdx.x, t = threadIdx.x;
    if (b == 0) blksum_scan_512(bsc, &totals[2], nbc, s, t);
    else        vscan1_512(rowcounts2, bsc2, b - 1, M, s, t);
}

// ---- MK3: blocks [0,nbc) vscan3(counts->start1) ; block nbc scan2(bsc2->totals[3]) ----
__global__ __launch_bounds__(512) void mk3_kernel(
    const uint32_t* __restrict__ counts, const uint32_t* __restrict__ bsc,
    uint32_t* __restrict__ start1,
    uint32_t* __restrict__ bsc2, uint32_t* __restrict__ totals,
    int M, int nbc) {
    __shared__ uint32_t s[512];
    int b = blockIdx.x, t = threadIdx.x;
    if (b < nbc) vscan3_512(counts, bsc, start1, b, M, s, t);
    else         blksum_scan_512(bsc2, &totals[3], nbc, s, t);
}

// ---- MK4: blocks [0,npb) perm scatter ; blocks [npb, npb+nbc) vscan3(rowcounts2->rowstart2)
__global__ __launch_bounds__(512) void mk4_kernel(
    const uint32_t* __restrict__ rank1_arr, const uint32_t* __restrict__ start1,
    uint32_t* __restrict__ cursor, uint32_t* __restrict__ perm,
    const uint32_t* __restrict__ rowcounts2, const uint32_t* __restrict__ bsc2,
    uint32_t* __restrict__ rowstart2, int M, int npb, int nbc) {
    int b = blockIdx.x, t = threadIdx.x;
    if (b < npb) {
        int i = b * 512 + t;
        if (i >= M) return;
        uint32_t r1 = rank1_arr[i];
        uint32_t slot = atomicAdd(&cursor[r1], 1u);
        perm[start1[r1] + slot] = i;
        return;
    }
    __shared__ uint32_t s[512];
    vscan3_512(rowcounts2, bsc2, rowstart2, b - npb, M, s, t);
}

// ------- flatten input rows into perm_f grouped by r2, group starts flagged bit31 -------
__global__ __launch_bounds__(512) void flatten_kernel(
    const uint32_t* __restrict__ parent_r2, const uint32_t* __restrict__ counts,
    const uint32_t* __restrict__ start1, const uint32_t* __restrict__ rowstart2,
    uint32_t* __restrict__ cursor2, const uint32_t* __restrict__ perm,
    uint32_t* __restrict__ perm_f, const uint32_t* __restrict__ totals, int M) {
    int i = blockIdx.x * 512 + threadIdx.x;
    if (i >= M) return;
    uint32_t U1 = totals[0];
    if ((uint32_t)i >= U1) return;
    uint32_t r2 = parent_r2[i];
    uint32_t cnt = counts[i];
    uint32_t base = atomicAdd(&cursor2[r2], cnt);
    uint32_t dst = rowstart2[r2] + base;
    uint32_t s = start1[i];
    perm_f[dst] = perm[s] | 0x80000000u;               // flag = start of relu group
    for (uint32_t q = 1; q < cnt; ++q) perm_f[dst + q] = perm[s + q];
}

// ---------------- bf16 MFMA GEMM: g = bf16( relu(X) @ W0 ) ----------------
// Barrier-free, one wave = one 16-row tile, grid-stride with 2-deep register
// prefetch (ping-pong pfA/pfB, explicitly unrolled so indexing is static).
// Wt in LDS fragment-major: every B-fragment is a conflict-free ds_read_b128
// with a compile-time immediate offset.
__device__ __forceinline__ void gemm_loadX(const float* __restrict__ X,
                                           int tile, int lm, int kg, float4* pf) {
    const char* xb = (const char*)X + ((size_t)tile*16 + lm)*512 + kg*32;
    #pragma unroll
    for (int ks = 0; ks < 4; ++ks) {
        pf[2*ks]   = *(const float4*)(xb + ks*128);
        pf[2*ks+1] = *(const float4*)(xb + ks*128 + 16);
    }
}

__device__ __forceinline__ void gemm_compute(const float4* pf, const char* wbase,
                                             ushort* __restrict__ g, int tile,
                                             int lm, int kg) {
    bf16x8 af[4];
    #pragma unroll
    for (int ks = 0; ks < 4; ++ks) {
        float4 a = pf[2*ks], b = pf[2*ks+1];
        union { uint32_t u[4]; bf16x8 v; } cv;
        cv.u[0] = f2bf1(fmaxf(a.x,0.f)) | (f2bf1(fmaxf(a.y,0.f)) << 16);
        cv.u[1] = f2bf1(fmaxf(a.z,0.f)) | (f2bf1(fmaxf(a.w,0.f)) << 16);
        cv.u[2] = f2bf1(fmaxf(b.x,0.f)) | (f2bf1(fmaxf(b.y,0.f)) << 16);
        cv.u[3] = f2bf1(fmaxf(b.z,0.f)) | (f2bf1(fmaxf(b.w,0.f)) << 16);
        af[ks] = cv.v;
    }
    ushort* grow = g + (size_t)((size_t)tile*16 + 4*kg)*128 + lm;
    #pragma unroll
    for (int n = 0; n < 8; ++n) {
        bf16x8 b0 = *(const bf16x8*)(wbase + n*256);
        bf16x8 b1 = *(const bf16x8*)(wbase + n*256 + 8192);
        bf16x8 b2 = *(const bf16x8*)(wbase + n*256 + 16384);
        bf16x8 b3 = *(const bf16x8*)(wbase + n*256 + 24576);
        f32x4 acc = (f32x4){0.f, 0.f, 0.f, 0.f};
        acc = __builtin_amdgcn_mfma_f32_16x16x32_bf16(af[0], b0, acc, 0, 0, 0);
        acc = __builtin_amdgcn_mfma_f32_16x16x32_bf16(af[1], b1, acc, 0, 0, 0);
        acc = __builtin_amdgcn_mfma_f32_16x16x32_bf16(af[2], b2, acc, 0, 0, 0);
        acc = __builtin_amdgcn_mfma_f32_16x16x32_bf16(af[3], b3, acc, 0, 0, 0);
        #pragma unroll
        for (int r = 0; r < 4; ++r)
            grow[(size_t)r*128 + 16*n] = (ushort)f2bf1(acc[r]);
    }
}

__global__ __launch_bounds__(256) void gemm_kernel(
    const float* __restrict__ X, const ushort* __restrict__ Wt,
    ushort* __restrict__ g, int M) {
    __shared__ __align__(16) ushort wlds[16384];       // 32 KB
    const int t = threadIdx.x;
    {
        // stage Wt: src chunk (row=16n+m, kc) -> dst [ks=kc>>2][kg=kc&3][n][m]
        int sm = t & 15, kc = t >> 4;                  // kc 0..15
        const char* src = (const char*)Wt;
        char* dst = (char*)wlds;
        #pragma unroll
        for (int n = 0; n < 8; ++n) {
            uint4 v = *(const uint4*)(src + n*4096 + sm*256 + kc*16);
            *(uint4*)(dst + (kc>>2)*8192 + (kc&3)*2048 + n*256 + sm*16) = v;
        }
    }
    __syncthreads();                                   // only barrier in kernel
    const int l = t & 63;
    const int lm = l & 15, kg = l >> 4;                // A-frag row / k-group
    const int ntiles = M >> 4;
    const int nw = gridDim.x * 4;
    int tile = blockIdx.x * 4 + (t >> 6);
    const char* wbase = (const char*)wlds + kg*2048 + lm*16;

    float4 pfA[8], pfB[8];
    if (tile < ntiles)      gemm_loadX(X, tile, lm, kg, pfA);
    if (tile + nw < ntiles) gemm_loadX(X, tile + nw, lm, kg, pfB);
    while (true) {
        // phase A: consume pfA(tile), prefetch tile+2nw into pfA
        if (tile >= ntiles) break;
        if (tile + 2*nw < ntiles) {
            // issue prefetch first? need pfA contents -> consume then refill:
        }
        {
            bf16x8 dummy; (void)dummy;
        }
        // consume A, then immediately refill A so its loads fly under phase B
        gemm_compute(pfA, wbase, g, tile, lm, kg);
        if (tile + 2*nw < ntiles) gemm_loadX(X, tile + 2*nw, lm, kg, pfA);
        tile += nw;
        // phase B
        if (tile >= ntiles) break;
        gemm_compute(pfB, wbase, g, tile, lm, kg);
        if (tile + 2*nw < ntiles) gemm_loadX(X, tile + 2*nw, lm, kg, pfB);
        tile += nw;
    }
}

// ---------------- flattened gather: out[j] = sum_groups relu(sum_rows g) -------------
// one wave per output row; row list is precomputed (perm_f), group starts flagged bit31
__global__ __launch_bounds__(256) void gather2_kernel(
    const uint32_t* __restrict__ rowstart2, const uint32_t* __restrict__ rowcounts2,
    const uint32_t* __restrict__ perm_f, const ushort* __restrict__ g,
    float* __restrict__ out, int M) {
    int wid = (blockIdx.x * 256 + threadIdx.x) >> 6;
    wid = __builtin_amdgcn_readfirstlane(wid);         // force wave-uniform SGPR
    int lane = threadIdx.x & 63;
    if (wid >= M) return;
    const uint32_t* G = (const uint32_t*)g;
    float accx = 0.f, accy = 0.f;
    uint32_t n = rowcounts2[wid];
    if (n) {
        uint32_t s = rowstart2[wid];
        // one coalesced load grabs up to 64 row entries for the whole wave
        uint32_t ev = (lane < (int)n) ? perm_f[s + lane] : 0u;
        float sx = 0.f, sy = 0.f;
        uint32_t ecur = (uint32_t)__shfl((int)ev, 0);
        uint32_t pk = G[(size_t)(ecur & 0x7FFFFFFFu) * 64 + lane];
        for (uint32_t q = 1; q < n; ++q) {
            uint32_t en = (q < 64u) ? (uint32_t)__shfl((int)ev, (int)q)
                                    : perm_f[s + q];
            // issue next row's load before consuming current (keeps 2 loads in flight)
            uint32_t pkn = G[(size_t)(en & 0x7FFFFFFFu) * 64 + lane];
            sx += __uint_as_float(pk << 16);
            sy += __uint_as_float(pk & 0xFFFF0000u);
            if (en >> 31) {                            // new relu group begins at row q
                accx += fmaxf(sx, 0.f); accy += fmaxf(sy, 0.f);
                sx = 0.f; sy = 0.f;
            }
            pk = pkn;
        }
        sx += __uint_as_float(pk << 16);
        sy += __uint_as_float(pk & 0xFFFF0000u);
        accx += fmaxf(sx, 0.f);
        accy += fmaxf(sy, 0.f);
    }
    float2 o; o.x = accx; o.y = accy;
    ((float2*)out)[(size_t)wid * 64 + lane] = o;
}

extern "C" void kernel_launch(void* const* d_in, const int* in_sizes, int n_in,
                              void* d_out, int out_size, void* d_ws, size_t ws_size,
                              hipStream_t stream) {
    const float* X      = (const float*)d_in[0];
    const int*   coords = (const int*)d_in[1];
    const float* W      = (const float*)d_in[2];
    const int M = in_sizes[0] / C;               // 400000

    const int NW1 = 1 << 19;                     // 2^24-bit bitmap -> 524288 words
    const int NW2 = 1 << 15;                     // 2^20-bit bitmap -> 32768 words
    const int NBC = (M + 1023) / 1024;           // 391 (1024 elems per scan block)
    const int NPB = (M + 511) / 512;             // 782 (512-thread element kernels)

    char* ws = (char*)d_ws;
    size_t off = 0;
    ushort*   g         = (ushort*)(ws + off);   off += (size_t)M * C * 2;   // 102.4 MB
    uint32_t* bm1       = (uint32_t*)(ws + off); off += (size_t)NW1 * 4;     // zeroed
    uint32_t* bm2       = (uint32_t*)(ws + off); off += (size_t)NW2 * 4;     // zeroed
    uint32_t* counts    = (uint32_t*)(ws + off); off += (size_t)M * 4;       // zeroed
    uint32_t* cursor    = (uint32_t*)(ws + off); off += (size_t)M * 4;       // zeroed
    uint32_t* rowcounts2= (uint32_t*)(ws + off); off += (size_t)M * 4;       // zeroed
    uint32_t* cursor2   = (uint32_t*)(ws + off); off += (size_t)M * 4;       // zeroed
    const size_t zero_off   = (size_t)M * C * 2;
    const size_t zero_bytes = off - zero_off;
    uint32_t* wp1       = (uint32_t*)(ws + off); off += (size_t)NW1 * 4;
    uint32_t* wp2       = (uint32_t*)(ws + off); off += (size_t)NW2 * 4;
    uint32_t* bs1       = (uint32_t*)(ws + off); off += 512 * 4;
    uint32_t* bs2       = (uint32_t*)(ws + off); off += 512 * 4;
    uint32_t* bsc       = (uint32_t*)(ws + off); off += 512 * 4;
    uint32_t* bsc2      = (uint32_t*)(ws + off); off += 512 * 4;
    uint32_t* totals    = (uint32_t*)(ws + off); off += 4 * 4;
    uint32_t* start1    = (uint32_t*)(ws + off); off += (size_t)M * 4;
    uint32_t* rank1_arr = (uint32_t*)(ws + off); off += (size_t)M * 4;
    uint32_t* perm      = (uint32_t*)(ws + off); off += (size_t)M * 4;
    uint32_t* parent_r2 = (uint32_t*)(ws + off); off += (size_t)M * 4;
    uint32_t* rowstart2 = (uint32_t*)(ws + off); off += (size_t)M * 4;
    ushort*   Wt        = (ushort*)(ws + off);   off += (size_t)C * C * 2;
    uint32_t* perm_f    = rank1_arr;             // rank1_arr dead after mk4 (perm)

    hipMemsetAsync(ws + zero_off, 0, zero_bytes, stream);

    // 1: mark bitmaps + convert W (merged)
    markconv_kernel<<<NPB + 32, 512, 0, stream>>>(coords, bm1, bm2, W, Wt, M, NPB);
    // 2-4: bitmap rank scans for bm1 and bm2 (merged per phase)
    mscan1_kernel<<<544, 512, 0, stream>>>(bm1, bs1, bm2, bs2);
    mscan2_kernel<<<2, 512, 0, stream>>>(bs1, bs2, totals);
    mscan3_kernel<<<544, 512, 0, stream>>>(bm1, bs1, wp1, bm2, bs2, wp2);
    // 5: per-row rank + counts
    count_kernel<<<NPB, 512, 0, stream>>>(coords, bm1, wp1, counts, rank1_arr, M);
    // 6-9: {vscan1(counts) || childsum}, {scan2(bsc) || vscan1(rowcounts2)},
    //      {vscan3(start1) || scan2(bsc2)}, {perm || vscan3(rowstart2)}
    mk1_kernel<<<NBC + NW1/512, 512, 0, stream>>>(counts, bsc, bm1, wp1, bm2, wp2,
                                                  parent_r2, rowcounts2, M, NBC, NW1);
    mk2_kernel<<<1 + NBC, 512, 0, stream>>>(bsc, totals, rowcounts2, bsc2, M, NBC);
    mk3_kernel<<<NBC + 1, 512, 0, stream>>>(counts, bsc, start1, bsc2, totals, M, NBC);
    mk4_kernel<<<NPB + NBC, 512, 0, stream>>>(rank1_arr, start1, cursor, perm,
                                              rowcounts2, bsc2, rowstart2, M, NPB, NBC);
    // 10: flatten rows grouped by r2
    flatten_kernel<<<NPB, 512, 0, stream>>>(
        parent_r2, counts, start1, rowstart2, cursor2, perm, perm_f, totals, M);
    // 11: GEMM, 12: gather
    gemm_kernel<<<1280, 256, 0, stream>>>(X, Wt, g, M);
    gather2_kernel<<<(M + 3) / 4, 256, 0, stream>>>(
        rowstart2, rowcounts2, perm_f, g, (float*)d_out, M);
}

// Round 4
// 278.743 us; speedup vs baseline: 1.7499x; 1.0577x over previous
//
#include <hip/hip_runtime.h>
#include <stdint.h>

#define C 128

typedef __attribute__((ext_vector_type(8))) short bf16x8;
typedef __attribute__((ext_vector_type(4))) float f32x4;

// f32 -> bf16 bits, round-to-nearest-even
__device__ __forceinline__ uint32_t f2bf1(float f) {
    uint32_t u = __float_as_uint(f);
    return (u + 0x7FFFu + ((u >> 16) & 1u)) >> 16;
}

// ---------------- key packing ----------------
// level-1 key: b1(1)<<23 | z1(5)<<18 | y1(9)<<9 | x1(9); numeric order == lexicographic
// level-2 key: z2(4)<<16 | y2(8)<<8 | x2(8)               (b2 == 0 for all real rows)

// ---- merged: zero the atomic buffers (blocks 0..nzb-1) + convert W -> Wt bf16 ----
// replaces hipMemsetAsync, whose rocclr fill kernel measured 117 us @ 74 GB/s (!)
__global__ __launch_bounds__(512) void zeroconv_kernel(
    uint4* __restrict__ zbase, int nquads,
    const float* __restrict__ W, ushort* __restrict__ Wt, int nzb) {
    int b = blockIdx.x, t = threadIdx.x;
    if (b < nzb) {
        int i = b * 512 + t;
        if (i < nquads) zbase[i] = (uint4){0u, 0u, 0u, 0u};
    } else {
        int id = (b - nzb) * 512 + t;                  // 0..16383
        int n = id >> 7, k = id & 127;
        Wt[id] = (ushort)f2bf1(W[k * C + n]);
    }
}

// ---- mark bitmap bits ----
__global__ __launch_bounds__(512) void mark_kernel(
    const int* __restrict__ coords, uint32_t* __restrict__ bm1,
    uint32_t* __restrict__ bm2, int M) {
    int i = blockIdx.x * 512 + threadIdx.x;
    if (i >= M) return;
    int bb = coords[4*i+0], z = coords[4*i+1], y = coords[4*i+2], x = coords[4*i+3];
    uint32_t k1 = ((uint32_t)(bb>>1)<<23) | ((uint32_t)(z>>1)<<18) |
                  ((uint32_t)(y>>1)<<9)  | (uint32_t)(x>>1);
    uint32_t k2 = ((uint32_t)(z>>2)<<16) | ((uint32_t)(y>>2)<<8) | (uint32_t)(x>>2);
    atomicOr(&bm1[k1>>5], 1u << (k1 & 31));
    atomicOr(&bm2[k2>>5], 1u << (k2 & 31));
}

// ---------------- shared device helpers (512-thread scan primitives) ----------------
__device__ __forceinline__ void bscan1_512(const uint32_t* bm, uint32_t* bs,
                                           int blk, uint32_t* s, int t) {
    int base = blk * 1024 + t * 2;
    uint32_t sum = __popc(bm[base]) + __popc(bm[base+1]);
    s[t] = sum;
    __syncthreads();
    for (int off = 256; off > 0; off >>= 1) {
        if (t < off) s[t] += s[t + off];
        __syncthreads();
    }
    if (t == 0) bs[blk] = s[0];
}

__device__ __forceinline__ void bscan3_512(const uint32_t* bm, const uint32_t* bs,
                                           uint32_t* wp, int blk, uint32_t* s, int t) {
    int base = blk * 1024 + t * 2;
    uint32_t p0 = __popc(bm[base]), p1 = __popc(bm[base+1]);
    uint32_t sum = p0 + p1;
    s[t] = sum;
    __syncthreads();
    for (int off = 1; off < 512; off <<= 1) {
        uint32_t add = (t >= off) ? s[t - off] : 0u;
        __syncthreads();
        s[t] += add;
        __syncthreads();
    }
    uint32_t ex = s[t] - sum + bs[blk];
    wp[base]   = ex;
    wp[base+1] = ex + p0;
}

// single-block exclusive scan of nb<=512 block sums, in place, writes total
__device__ __forceinline__ void blksum_scan_512(uint32_t* bs, uint32_t* total,
                                                int nb, uint32_t* s, int t) {
    uint32_t v = (t < nb) ? bs[t] : 0u;
    s[t] = v;
    __syncthreads();
    for (int off = 1; off < 512; off <<= 1) {
        uint32_t add = (t >= off) ? s[t - off] : 0u;
        __syncthreads();
        s[t] += add;
        __syncthreads();
    }
    if (t < nb) bs[t] = s[t] - v;
    if (t == nb - 1) *total = s[t];
}

__device__ __forceinline__ void vscan1_512(const uint32_t* v, uint32_t* bs,
                                           int blk, int n, uint32_t* s, int t) {
    int base = blk * 1024 + t * 2;
    uint32_t sum = 0;
    if (base     < n) sum += v[base];
    if (base + 1 < n) sum += v[base+1];
    s[t] = sum;
    __syncthreads();
    for (int off = 256; off > 0; off >>= 1) {
        if (t < off) s[t] += s[t + off];
        __syncthreads();
    }
    if (t == 0) bs[blk] = s[0];
}

__device__ __forceinline__ void vscan3_512(const uint32_t* v, const uint32_t* bs,
                                           uint32_t* ex_out, int blk, int n,
                                           uint32_t* s, int t) {
    int base = blk * 1024 + t * 2;
    uint32_t p0 = (base     < n) ? v[base]   : 0u;
    uint32_t p1 = (base + 1 < n) ? v[base+1] : 0u;
    uint32_t sum = p0 + p1;
    s[t] = sum;
    __syncthreads();
    for (int off = 1; off < 512; off <<= 1) {
        uint32_t add = (t >= off) ? s[t - off] : 0u;
        __syncthreads();
        s[t] += add;
        __syncthreads();
    }
    uint32_t e = s[t] - sum + bs[blk];
    if (base     < n) ex_out[base]   = e;
    if (base + 1 < n) ex_out[base+1] = e + p0;
}

// ---- merged bitmap scan phases: blocks [0,512) -> bm1, [512,544) -> bm2 ----
__global__ __launch_bounds__(512) void mscan1_kernel(
    const uint32_t* __restrict__ bm1, uint32_t* __restrict__ bs1,
    const uint32_t* __restrict__ bm2, uint32_t* __restrict__ bs2) {
    __shared__ uint32_t s[512];
    int b = blockIdx.x, t = threadIdx.x;
    if (b < 512) bscan1_512(bm1, bs1, b, s, t);
    else         bscan1_512(bm2, bs2, b - 512, s, t);
}

__global__ __launch_bounds__(512) void mscan2_kernel(
    uint32_t* __restrict__ bs1, uint32_t* __restrict__ bs2,
    uint32_t* __restrict__ totals) {
    __shared__ uint32_t s[512];
    int t = threadIdx.x;
    if (blockIdx.x == 0) blksum_scan_512(bs1, &totals[0], 512, s, t);
    else                 blksum_scan_512(bs2, &totals[1], 32,  s, t);
}

__global__ __launch_bounds__(512) void mscan3_kernel(
    const uint32_t* __restrict__ bm1, const uint32_t* __restrict__ bs1,
    uint32_t* __restrict__ wp1,
    const uint32_t* __restrict__ bm2, const uint32_t* __restrict__ bs2,
    uint32_t* __restrict__ wp2) {
    __shared__ uint32_t s[512];
    int b = blockIdx.x, t = threadIdx.x;
    if (b < 512) bscan3_512(bm1, bs1, wp1, b, s, t);
    else         bscan3_512(bm2, bs2, wp2, b - 512, s, t);
}

// per input row: rank1 -> counts + rank cache; atomic return value IS the slot
__global__ __launch_bounds__(512) void count_kernel(
    const int* __restrict__ coords, const uint32_t* __restrict__ bm1,
    const uint32_t* __restrict__ wp1, uint32_t* __restrict__ counts,
    uint32_t* __restrict__ rank1_arr, uint32_t* __restrict__ slot1, int M) {
    int i = blockIdx.x * 512 + threadIdx.x;
    if (i >= M) return;
    int b = coords[4*i+0], z = coords[4*i+1], y = coords[4*i+2], x = coords[4*i+3];
    uint32_t k1 = ((uint32_t)(b>>1)<<23) | ((uint32_t)(z>>1)<<18) |
                  ((uint32_t)(y>>1)<<9)  | (uint32_t)(x>>1);
    uint32_t r1 = wp1[k1>>5] + __popc(bm1[k1>>5] & ((1u << (k1 & 31)) - 1u));
    rank1_arr[i] = r1;
    slot1[i] = atomicAdd(&counts[r1], 1u);
}

// ---- MK1: blocks [0,nbc) vscan1(counts) ; [nbc, nbc+1024) childsum over bm1 words ----
// childsum atomic return value IS the child's base offset inside the parent segment
__global__ __launch_bounds__(512) void mk1_kernel(
    const uint32_t* __restrict__ counts, uint32_t* __restrict__ bsc,
    const uint32_t* __restrict__ bm1, const uint32_t* __restrict__ wp1,
    const uint32_t* __restrict__ bm2, const uint32_t* __restrict__ wp2,
    uint32_t* __restrict__ parent_r2, uint32_t* __restrict__ rowcounts2,
    uint32_t* __restrict__ childbase, int M, int nbc, int nwords) {
    int b = blockIdx.x, t = threadIdx.x;
    if (b < nbc) {
        __shared__ uint32_t s[512];
        vscan1_512(counts, bsc, b, M, s, t);
        return;
    }
    int w = (b - nbc) * 512 + t;
    if (w >= nwords) return;
    uint32_t bits = bm1[w];
    if (!bits) return;
    uint32_t r1 = wp1[w];
    while (bits) {
        int bit = __ffs(bits) - 1;
        uint32_t k1 = ((uint32_t)w << 5) | (uint32_t)bit;
        uint32_t z1 = (k1 >> 18) & 31u, y1 = (k1 >> 9) & 511u, x1 = k1 & 511u;
        uint32_t k2 = ((z1 >> 1) << 16) | ((y1 >> 1) << 8) | (x1 >> 1);
        uint32_t word2 = bm2[k2 >> 5];
        uint32_t r2 = wp2[k2 >> 5] + __popc(word2 & ((1u << (k2 & 31)) - 1u));
        parent_r2[r1] = r2;
        childbase[r1] = atomicAdd(&rowcounts2[r2], counts[r1]);
        r1++;
        bits &= bits - 1;
    }
}

// ---- MK2: block 0 scan2(bsc->totals[2]) ; blocks [1,1+nbc) vscan1(rowcounts2) ----
__global__ __launch_bounds__(512) void mk2_kernel(
    uint32_t* __restrict__ bsc, uint32_t* __restrict__ totals,
    const uint32_t* __restrict__ rowcounts2, uint32_t* __restrict__ bsc2,
    int M, int nbc) {
    __shared__ uint32_t s[512];
    int b = blockIdx.x, t = threadIdx.x;
    if (b == 0) blksum_scan_512(bsc, &totals[2], nbc, s, t);
    else        vscan1_512(rowcounts2, bsc2, b - 1, M, s, t);
}

// ---- MK3: blocks [0,nbc) vscan3(counts->start1) ; block nbc scan2(bsc2->totals[3]) ----
__global__ __launch_bounds__(512) void mk3_kernel(
    const uint32_t* __restrict__ counts, const uint32_t* __restrict__ bsc,
    uint32_t* __restrict__ start1,
    uint32_t* __restrict__ bsc2, uint32_t* __restrict__ totals,
    int M, int nbc) {
    __shared__ uint32_t s[512];
    int b = blockIdx.x, t = threadIdx.x;
    if (b < nbc) vscan3_512(counts, bsc, start1, b, M, s, t);
    else         blksum_scan_512(bsc2, &totals[3], nbc, s, t);
}

// ---- MK4: blocks [0,npb) perm scatter (no atomic) ;
//           blocks [npb, npb+nbc) vscan3(rowcounts2->rowstart2) ----
__global__ __launch_bounds__(512) void mk4_kernel(
    const uint32_t* __restrict__ rank1_arr, const uint32_t* __restrict__ start1,
    const uint32_t* __restrict__ slot1, uint32_t* __restrict__ perm,
    const uint32_t* __restrict__ rowcounts2, const uint32_t* __restrict__ bsc2,
    uint32_t* __restrict__ rowstart2, int M, int npb, int nbc) {
    int b = blockIdx.x, t = threadIdx.x;
    if (b < npb) {
        int i = b * 512 + t;
        if (i >= M) return;
        uint32_t r1 = rank1_arr[i];
        perm[start1[r1] + slot1[i]] = i;
        return;
    }
    __shared__ uint32_t s[512];
    vscan3_512(rowcounts2, bsc2, rowstart2, b - npb, M, s, t);
}

// ------- flatten input rows into perm_f grouped by r2, group starts flagged bit31 -------
__global__ __launch_bounds__(512) void flatten_kernel(
    const uint32_t* __restrict__ parent_r2, const uint32_t* __restrict__ counts,
    const uint32_t* __restrict__ start1, const uint32_t* __restrict__ rowstart2,
    const uint32_t* __restrict__ childbase, const uint32_t* __restrict__ perm,
    uint32_t* __restrict__ perm_f, const uint32_t* __restrict__ totals, int M) {
    int i = blockIdx.x * 512 + threadIdx.x;
    if (i >= M) return;
    uint32_t U1 = totals[0];
    if ((uint32_t)i >= U1) return;
    uint32_t r2 = parent_r2[i];
    uint32_t cnt = counts[i];
    uint32_t dst = rowstart2[r2] + childbase[i];
    uint32_t s = start1[i];
    perm_f[dst] = perm[s] | 0x80000000u;               // flag = start of relu group
    for (uint32_t q = 1; q < cnt; ++q) perm_f[dst + q] = perm[s + q];
}

// ---------------- bf16 MFMA GEMM: g = bf16( relu(X) @ W0 ) ----------------
// Barrier-free, one wave = one 16-row tile, grid-stride with 2-deep register
// prefetch (ping-pong pfA/pfB, explicitly unrolled so indexing is static).
// Wt in LDS fragment-major: every B-fragment is a conflict-free ds_read_b128
// with a compile-time immediate offset.
__device__ __forceinline__ void gemm_loadX(const float* __restrict__ X,
                                           int tile, int lm, int kg, float4* pf) {
    const char* xb = (const char*)X + ((size_t)tile*16 + lm)*512 + kg*32;
    #pragma unroll
    for (int ks = 0; ks < 4; ++ks) {
        pf[2*ks]   = *(const float4*)(xb + ks*128);
        pf[2*ks+1] = *(const float4*)(xb + ks*128 + 16);
    }
}

__device__ __forceinline__ void gemm_compute(const float4* pf, const char* wbase,
                                             ushort* __restrict__ g, int tile,
                                             int lm, int kg) {
    bf16x8 af[4];
    #pragma unroll
    for (int ks = 0; ks < 4; ++ks) {
        float4 a = pf[2*ks], b = pf[2*ks+1];
        union { uint32_t u[4]; bf16x8 v; } cv;
        cv.u[0] = f2bf1(fmaxf(a.x,0.f)) | (f2bf1(fmaxf(a.y,0.f)) << 16);
        cv.u[1] = f2bf1(fmaxf(a.z,0.f)) | (f2bf1(fmaxf(a.w,0.f)) << 16);
        cv.u[2] = f2bf1(fmaxf(b.x,0.f)) | (f2bf1(fmaxf(b.y,0.f)) << 16);
        cv.u[3] = f2bf1(fmaxf(b.z,0.f)) | (f2bf1(fmaxf(b.w,0.f)) << 16);
        af[ks] = cv.v;
    }
    ushort* grow = g + (size_t)((size_t)tile*16 + 4*kg)*128 + lm;
    #pragma unroll
    for (int n = 0; n < 8; ++n) {
        bf16x8 b0 = *(const bf16x8*)(wbase + n*256);
        bf16x8 b1 = *(const bf16x8*)(wbase + n*256 + 8192);
        bf16x8 b2 = *(const bf16x8*)(wbase + n*256 + 16384);
        bf16x8 b3 = *(const bf16x8*)(wbase + n*256 + 24576);
        f32x4 acc = (f32x4){0.f, 0.f, 0.f, 0.f};
        acc = __builtin_amdgcn_mfma_f32_16x16x32_bf16(af[0], b0, acc, 0, 0, 0);
        acc = __builtin_amdgcn_mfma_f32_16x16x32_bf16(af[1], b1, acc, 0, 0, 0);
        acc = __builtin_amdgcn_mfma_f32_16x16x32_bf16(af[2], b2, acc, 0, 0, 0);
        acc = __builtin_amdgcn_mfma_f32_16x16x32_bf16(af[3], b3, acc, 0, 0, 0);
        #pragma unroll
        for (int r = 0; r < 4; ++r)
            grow[(size_t)r*128 + 16*n] = (ushort)f2bf1(acc[r]);
    }
}

__global__ __launch_bounds__(256) void gemm_kernel(
    const float* __restrict__ X, const ushort* __restrict__ Wt,
    ushort* __restrict__ g, int M) {
    __shared__ __align__(16) ushort wlds[16384];       // 32 KB
    const int t = threadIdx.x;
    {
        // stage Wt: src chunk (row=16n+m, kc) -> dst [ks=kc>>2][kg=kc&3][n][m]
        int sm = t & 15, kc = t >> 4;                  // kc 0..15
        const char* src = (const char*)Wt;
        char* dst = (char*)wlds;
        #pragma unroll
        for (int n = 0; n < 8; ++n) {
            uint4 v = *(const uint4*)(src + n*4096 + sm*256 + kc*16);
            *(uint4*)(dst + (kc>>2)*8192 + (kc&3)*2048 + n*256 + sm*16) = v;
        }
    }
    __syncthreads();                                   // only barrier in kernel
    const int l = t & 63;
    const int lm = l & 15, kg = l >> 4;                // A-frag row / k-group
    const int ntiles = M >> 4;
    const int nw = gridDim.x * 4;
    int tile = blockIdx.x * 4 + (t >> 6);
    const char* wbase = (const char*)wlds + kg*2048 + lm*16;

    float4 pfA[8], pfB[8];
    if (tile < ntiles)      gemm_loadX(X, tile, lm, kg, pfA);
    if (tile + nw < ntiles) gemm_loadX(X, tile + nw, lm, kg, pfB);
    while (true) {
        if (tile >= ntiles) break;
        // consume A, then immediately refill A so its loads fly under phase B
        gemm_compute(pfA, wbase, g, tile, lm, kg);
        if (tile + 2*nw < ntiles) gemm_loadX(X, tile + 2*nw, lm, kg, pfA);
        tile += nw;
        if (tile >= ntiles) break;
        gemm_compute(pfB, wbase, g, tile, lm, kg);
        if (tile + 2*nw < ntiles) gemm_loadX(X, tile + 2*nw, lm, kg, pfB);
        tile += nw;
    }
}

// ---------------- flattened gather: out[j] = sum_groups relu(sum_rows g) -------------
// one wave per output row; row list is precomputed (perm_f), group starts flagged bit31
__global__ __launch_bounds__(256) void gather2_kernel(
    const uint32_t* __restrict__ rowstart2, const uint32_t* __restrict__ rowcounts2,
    const uint32_t* __restrict__ perm_f, const ushort* __restrict__ g,
    float* __restrict__ out, int M) {
    int wid = (blockIdx.x * 256 + threadIdx.x) >> 6;
    wid = __builtin_amdgcn_readfirstlane(wid);         // force wave-uniform SGPR
    int lane = threadIdx.x & 63;
    if (wid >= M) return;
    const uint32_t* G = (const uint32_t*)g;
    float accx = 0.f, accy = 0.f;
    uint32_t n = rowcounts2[wid];
    if (n) {
        uint32_t s = rowstart2[wid];
        // one coalesced load grabs up to 64 row entries for the whole wave
        uint32_t ev = (lane < (int)n) ? perm_f[s + lane] : 0u;
        float sx = 0.f, sy = 0.f;
        uint32_t ecur = (uint32_t)__shfl((int)ev, 0);
        uint32_t pk = G[(size_t)(ecur & 0x7FFFFFFFu) * 64 + lane];
        for (uint32_t q = 1; q < n; ++q) {
            uint32_t en = (q < 64u) ? (uint32_t)__shfl((int)ev, (int)q)
                                    : perm_f[s + q];
            // issue next row's load before consuming current (keeps 2 loads in flight)
            uint32_t pkn = G[(size_t)(en & 0x7FFFFFFFu) * 64 + lane];
            sx += __uint_as_float(pk << 16);
            sy += __uint_as_float(pk & 0xFFFF0000u);
            if (en >> 31) {                            // new relu group begins at row q
                accx += fmaxf(sx, 0.f); accy += fmaxf(sy, 0.f);
                sx = 0.f; sy = 0.f;
            }
            pk = pkn;
        }
        sx += __uint_as_float(pk << 16);
        sy += __uint_as_float(pk & 0xFFFF0000u);
        accx += fmaxf(sx, 0.f);
        accy += fmaxf(sy, 0.f);
    }
    float2 o; o.x = accx; o.y = accy;
    ((float2*)out)[(size_t)wid * 64 + lane] = o;
}

extern "C" void kernel_launch(void* const* d_in, const int* in_sizes, int n_in,
                              void* d_out, int out_size, void* d_ws, size_t ws_size,
                              hipStream_t stream) {
    const float* X      = (const float*)d_in[0];
    const int*   coords = (const int*)d_in[1];
    const float* W      = (const float*)d_in[2];
    const int M = in_sizes[0] / C;               // 400000

    const int NW1 = 1 << 19;                     // 2^24-bit bitmap -> 524288 words
    const int NW2 = 1 << 15;                     // 2^20-bit bitmap -> 32768 words
    const int NBC = (M + 1023) / 1024;           // 391 (1024 elems per scan block)
    const int NPB = (M + 511) / 512;             // 782 (512-thread element kernels)

    char* ws = (char*)d_ws;
    size_t off = 0;
    ushort*   g         = (ushort*)(ws + off);   off += (size_t)M * C * 2;   // 102.4 MB
    // ---- contiguous zeroed region: bm1 | bm2 | counts | rowcounts2 ----
    uint32_t* bm1       = (uint32_t*)(ws + off); off += (size_t)NW1 * 4;
    uint32_t* bm2       = (uint32_t*)(ws + off); off += (size_t)NW2 * 4;
    uint32_t* counts    = (uint32_t*)(ws + off); off += (size_t)M * 4;
    uint32_t* rowcounts2= (uint32_t*)(ws + off); off += (size_t)M * 4;
    const size_t zero_off   = (size_t)M * C * 2;
    const size_t zero_bytes = off - zero_off;            // 5,428,224 B (16B multiple)
    // ---- never-zeroed scratch ----
    uint32_t* wp1       = (uint32_t*)(ws + off); off += (size_t)NW1 * 4;
    uint32_t* wp2       = (uint32_t*)(ws + off); off += (size_t)NW2 * 4;
    uint32_t* bs1       = (uint32_t*)(ws + off); off += 512 * 4;
    uint32_t* bs2       = (uint32_t*)(ws + off); off += 512 * 4;
    uint32_t* bsc       = (uint32_t*)(ws + off); off += 512 * 4;
    uint32_t* bsc2      = (uint32_t*)(ws + off); off += 512 * 4;
    uint32_t* totals    = (uint32_t*)(ws + off); off += 4 * 4;
    uint32_t* start1    = (uint32_t*)(ws + off); off += (size_t)M * 4;
    uint32_t* rank1_arr = (uint32_t*)(ws + off); off += (size_t)M * 4;
    uint32_t* slot1     = (uint32_t*)(ws + off); off += (size_t)M * 4;
    uint32_t* perm      = (uint32_t*)(ws + off); off += (size_t)M * 4;
    uint32_t* parent_r2 = (uint32_t*)(ws + off); off += (size_t)M * 4;
    uint32_t* childbase = (uint32_t*)(ws + off); off += (size_t)M * 4;
    uint32_t* rowstart2 = (uint32_t*)(ws + off); off += (size_t)M * 4;
    ushort*   Wt        = (ushort*)(ws + off);   off += (size_t)C * C * 2;
    uint32_t* perm_f    = rank1_arr;             // rank1_arr dead after mk4 (perm)

    const int NQ  = (int)(zero_bytes / 16);      // uint4 quads to zero
    const int NZB = (NQ + 511) / 512;            // zero blocks

    // 1: zero atomic buffers + convert W (merged; replaces hipMemsetAsync)
    zeroconv_kernel<<<NZB + 32, 512, 0, stream>>>((uint4*)(ws + zero_off), NQ, W, Wt, NZB);
    // 2: mark bitmaps
    mark_kernel<<<NPB, 512, 0, stream>>>(coords, bm1, bm2, M);
    // 3-5: bitmap rank scans for bm1 and bm2 (merged per phase)
    mscan1_kernel<<<544, 512, 0, stream>>>(bm1, bs1, bm2, bs2);
    mscan2_kernel<<<2, 512, 0, stream>>>(bs1, bs2, totals);
    mscan3_kernel<<<544, 512, 0, stream>>>(bm1, bs1, wp1, bm2, bs2, wp2);
    // 6: per-row rank + counts (+ slot via atomic return)
    count_kernel<<<NPB, 512, 0, stream>>>(coords, bm1, wp1, counts, rank1_arr, slot1, M);
    // 7-10: {vscan1(counts) || childsum}, {scan2(bsc) || vscan1(rowcounts2)},
    //       {vscan3(start1) || scan2(bsc2)}, {perm || vscan3(rowstart2)}
    mk1_kernel<<<NBC + NW1/512, 512, 0, stream>>>(counts, bsc, bm1, wp1, bm2, wp2,
                                                  parent_r2, rowcounts2, childbase,
                                                  M, NBC, NW1);
    mk2_kernel<<<1 + NBC, 512, 0, stream>>>(bsc, totals, rowcounts2, bsc2, M, NBC);
    mk3_kernel<<<NBC + 1, 512, 0, stream>>>(counts, bsc, start1, bsc2, totals, M, NBC);
    mk4_kernel<<<NPB + NBC, 512, 0, stream>>>(rank1_arr, start1, slot1, perm,
                                              rowcounts2, bsc2, rowstart2, M, NPB, NBC);
    // 11: flatten rows grouped by r2 (atomic-free)
    flatten_kernel<<<NPB, 512, 0, stream>>>(
        parent_r2, counts, start1, rowstart2, childbase, perm, perm_f, totals, M);
    // 12: GEMM, 13: gather
    gemm_kernel<<<1280, 256, 0, stream>>>(X, Wt, g, M);
    gather2_kernel<<<(M + 3) / 4, 256, 0, stream>>>(
        rowstart2, rowcounts2, perm_f, g, (float*)d_out, M);
}